// Round 13
// baseline (172.165 us; speedup 1.0000x reference)
//
#include <hip/hip_runtime.h>
#include <hip/hip_bf16.h>

#define DD 256
#define RR 32
#define CC 64
#define PB 96
#define NT 1024

typedef __attribute__((ext_vector_type(8))) short short8;
typedef __attribute__((ext_vector_type(4))) float f32x4;

__device__ __forceinline__ short f2bf(float f) {
    return __builtin_bit_cast(short, __float2bfloat16(f));
}
__device__ __forceinline__ float b2f(unsigned short s) {
    union { unsigned u; float f; } v; v.u = ((unsigned)s) << 16;
    return v.f;
}

// [64][256] bf16: 8-elem-block XOR swizzle by (row&7)
__device__ __forceinline__ int hswz(int c, int d) {
    return c * 256 + (d ^ ((c & 7) << 3));
}
// [*][32] bf16: 8-elem-block XOR swizzle by ((row>>1)&3)
__device__ __forceinline__ int nswz(int r, int k) {
    return r * 32 + (k ^ (((r >> 1) & 3) << 3));
}

// ============ prep kernel: gWd^T swizzled image + QKVG/Wu MFMA B-fragments + fp32 transposes ============
// Fragment layout (16x16x32 B operand): frag f, lane l, j=0..7 -> B[n=(l&15)][k=(l>>4)*8+j]
__global__ __launch_bounds__(1024, 1)
void prep_kernel(const float* __restrict__ ln_g, const float* __restrict__ ln_b,
                 const float* __restrict__ Wd, const float* __restrict__ bd,
                 const float* __restrict__ Wq, const float* __restrict__ Wk,
                 const float* __restrict__ Wv, const float* __restrict__ Wg,
                 const float* __restrict__ Wu,
                 const float* __restrict__ W1, const float* __restrict__ W2,
                 short* __restrict__ wsWd, short* __restrict__ wsF2,
                 short* __restrict__ wsF3, float* __restrict__ wsLN,
                 float* __restrict__ wsW1T, float* __restrict__ wsW2T)
{
    __shared__ float redp[2048];
    const int t = threadIdx.x;
    {   // gWd^T swizzled image + ln-fold partials
        const int r = t >> 5, dblk = t & 31;
        short8 vv;
        float sa = 0.f, sb = 0.f;
        #pragma unroll
        for (int j = 0; j < 8; ++j) {
            const int d = dblk * 8 + j;
            const float wd = Wd[d * RR + r];
            const float g  = ln_g[d];
            vv[j] = f2bf(g * wd);
            sa += g * wd;
            sb += ln_b[d] * wd;
        }
        *(short8*)&wsWd[r * 256 + ((dblk ^ (r & 7)) << 3)] = vv;
        redp[r * 32 + dblk]        = sa;
        redp[1024 + r * 32 + dblk] = sb;
    }
    if (t < 512) {  // wsF2: QKVG B-frags, f = m*2+half
        const int f = t >> 6, l = t & 63;
        const int m = f >> 1, half = f & 1;
        const float* Wm = (m == 0) ? Wq : (m == 1) ? Wk : (m == 2) ? Wv : Wg;
        const int rout = half * 16 + (l & 15);
        short8 v;
        #pragma unroll
        for (int j = 0; j < 8; ++j) {
            const int rin = (l >> 4) * 8 + j;
            v[j] = f2bf(Wm[rin * RR + rout]);
        }
        *(short8*)&wsF2[f * 512 + l * 8] = v;
    }
    {   // wsF3: Wu B-frags, f = dt (16 frags)
        const int f = t >> 6, l = t & 63;
        const int d = f * 16 + (l & 15);
        short8 v;
        #pragma unroll
        for (int j = 0; j < 8; ++j) {
            const int r = (l >> 4) * 8 + j;
            v[j] = f2bf(Wu[r * DD + d]);
        }
        *(short8*)&wsF3[f * 512 + l * 8] = v;
    }
    #pragma unroll
    for (int rep = 0; rep < 16; ++rep) {   // W1T[j][d] (64x256 fp32)
        const int id = rep * 1024 + t;
        const int j = id >> 8, d = id & 255;
        wsW1T[j * 256 + d] = W1[d * 64 + j];
    }
    #pragma unroll
    for (int rep = 0; rep < 16; ++rep) {   // W2T[d][j] (256x64 fp32)
        const int id = rep * 1024 + t;
        const int d = id >> 6, j = id & 63;
        wsW2T[d * 64 + j] = W2[j * 256 + d];
    }
    __syncthreads();
    if (t < 32) {
        float s = 0.f;
        #pragma unroll
        for (int g = 0; g < 32; ++g) s += redp[t * 32 + g];
        wsLN[t] = s;                       // ln_a
    } else if (t < 64) {
        const int r = t - 32;
        float s = 0.f;
        #pragma unroll
        for (int g = 0; g < 32; ++g) s += redp[1024 + r * 32 + g];
        wsLN[t] = s + bd[r];               // ln_bv
    }
}

// ================= main kernel: 4 barriers, wave-local fused chains =================
__global__ __launch_bounds__(NT, 8)
void hydra_kernel(const float* __restrict__ x,
                  const short* __restrict__ wsWd, const short* __restrict__ wsF2,
                  const short* __restrict__ wsF3, const float* __restrict__ wsLN,
                  const float* __restrict__ wsW1T, const float* __restrict__ wsW2T,
                  const float* __restrict__ bg, const float* __restrict__ bu,
                  const float* __restrict__ b1, const float* __restrict__ b2,
                  float* __restrict__ out)
{
    __shared__ short hbf[CC * DD];      // 32 KB h tile bf16 swizzled (residual source, live to end)
    __shared__ short wreg[RR * DD];     // 16 KB gWd^T (P0->P1 only)
    __shared__ short qg[CC * RR];       // 4 KB  Q_n*G bf16 [c][r]
    __shared__ short lowbuf[CC * RR];   // 4 KB  hlow (P1) -> Abuf (P2+)
    __shared__ float redA[1024];        // 4 KB  LN partials [c][8][2]
    __shared__ float gfp[128];          // 512B  gf partials [4][32]
    __shared__ float cv_s[DD], gate_s[DD];
    __shared__ float mu_s[CC], rstd_s[CC];
    __shared__ float hid_s[64];
    __shared__ float ln_a[RR], ln_bv[RR];

    const int t    = threadIdx.x;
    const int lane = t & 63;
    const int w    = t >> 6;
    const int bp   = blockIdx.x;
    const int b    = bp / PB;
    const int p    = bp - b * PB;
    const size_t rowbase = (size_t)(b * CC) * PB * DD + (size_t)p * DD;

    // ---- P0: load x -> hbf bf16 swizzled; LN partials; copy gWd^T; ln vectors ----
    #pragma unroll
    for (int i = 0; i < 4; ++i) {
        const int c = w * 4 + i;
        const float4 v = *(const float4*)(x + rowbase + (size_t)c * (PB * DD) + 4 * lane);
        float s1 = v.x + v.y + v.z + v.w;
        float s2 = v.x * v.x + v.y * v.y + v.z * v.z + v.w * v.w;
        s1 += __shfl_xor(s1, 1, 64); s2 += __shfl_xor(s2, 1, 64);
        s1 += __shfl_xor(s1, 2, 64); s2 += __shfl_xor(s2, 2, 64);
        s1 += __shfl_xor(s1, 4, 64); s2 += __shfl_xor(s2, 4, 64);
        if ((lane & 7) == 0)
            *(float2*)&redA[(c * 8 + (lane >> 3)) * 2] = make_float2(s1, s2);
        ushort4 pk;
        pk.x = (unsigned short)f2bf(v.x); pk.y = (unsigned short)f2bf(v.y);
        pk.z = (unsigned short)f2bf(v.z); pk.w = (unsigned short)f2bf(v.w);
        *(ushort4*)&hbf[hswz(c, 4 * lane)] = pk;
    }
    *(short8*)&wreg[t * 8] = *(const short8*)&wsWd[t * 8];
    if (t < 32)              ln_a[t]       = wsLN[t];
    else if (t < 64)         ln_bv[t - 32] = wsLN[t];
    __syncthreads();

    // ---- P1: [w0-3] wave-local chain: LN fin -> S3 MFMA x16 -> epilogue -> QKVG MFMA x8 -> qg/gf
    //          [t256-383] chan_var direct (2 cols each) ----
    if (w < 4) {
        const int ct = w;
        if (lane < 16) {   // LN finalize for own rows
            const int c = ct * 16 + lane;
            float s1 = 0.f, s2 = 0.f;
            #pragma unroll
            for (int g = 0; g < 8; ++g) {
                const float2 pr = *(const float2*)&redA[(c * 8 + g) * 2];
                s1 += pr.x; s2 += pr.y;
            }
            const float mu = s1 * (1.f / 256.f);
            mu_s[c]   = mu;
            rstd_s[c] = rsqrtf(s2 * (1.f / 256.f) - mu * mu + 1e-5f);
        }
        const int arow = ct * 16 + (lane & 15);
        const int kofs = (lane >> 4) * 8;
        const int col0 = lane & 15, col1 = 16 + col0;
        // S3: 16 MFMAs (both column halves)
        f32x4 s3a0 = {0,0,0,0}, s3a1 = {0,0,0,0};
        #pragma unroll
        for (int step = 0; step < 8; ++step) {
            const short8 a  = *(const short8*)&hbf[hswz(arow, step * 32 + kofs)];
            const short8 b0 = *(const short8*)&wreg[hswz(col0, step * 32 + kofs)];
            const short8 b1f= *(const short8*)&wreg[hswz(col1, step * 32 + kofs)];
            s3a0 = __builtin_amdgcn_mfma_f32_16x16x32_bf16(a, b0, s3a0, 0, 0, 0);
            s3a1 = __builtin_amdgcn_mfma_f32_16x16x32_bf16(a, b1f, s3a1, 0, 0, 0);
        }
        // epilogue -> lowbuf (wave-local)
        {
            const float la0 = ln_a[col0], lb0 = ln_bv[col0];
            const float la1 = ln_a[col1], lb1 = ln_bv[col1];
            #pragma unroll
            for (int i = 0; i < 4; ++i) {
                const int c = ct * 16 + (lane >> 4) * 4 + i;
                const float rs = rstd_s[c], mu = mu_s[c];
                lowbuf[nswz(c, col0)] = f2bf(rs * s3a0[i] - rs * mu * la0 + lb0);
                lowbuf[nswz(c, col1)] = f2bf(rs * s3a1[i] - rs * mu * la1 + lb1);
            }
        }
        // QKVG (staged to bound VGPR): A-frag wave-local from lowbuf; B-frags L2-direct
        const short8 av = *(const short8*)&lowbuf[nswz(arow, kofs)];
        f32x4 aQ0={0,0,0,0}, aQ1={0,0,0,0}, aK0={0,0,0,0}, aK1={0,0,0,0};
        {
            const short8 bQ0 = *(const short8*)(wsF2 + 0 * 512 + lane * 8);
            const short8 bQ1 = *(const short8*)(wsF2 + 1 * 512 + lane * 8);
            const short8 bK0 = *(const short8*)(wsF2 + 2 * 512 + lane * 8);
            const short8 bK1 = *(const short8*)(wsF2 + 3 * 512 + lane * 8);
            aQ0 = __builtin_amdgcn_mfma_f32_16x16x32_bf16(av, bQ0, aQ0, 0, 0, 0);
            aQ1 = __builtin_amdgcn_mfma_f32_16x16x32_bf16(av, bQ1, aQ1, 0, 0, 0);
            aK0 = __builtin_amdgcn_mfma_f32_16x16x32_bf16(av, bK0, aK0, 0, 0, 0);
            aK1 = __builtin_amdgcn_mfma_f32_16x16x32_bf16(av, bK1, aK1, 0, 0, 0);
        }
        float qs[4], ks[4];
        #pragma unroll
        for (int i = 0; i < 4; ++i) {
            float sq = aQ0[i] * aQ0[i] + aQ1[i] * aQ1[i];
            float sk = aK0[i] * aK0[i] + aK1[i] * aK1[i];
            sq += __shfl_xor(sq, 1, 64); sk += __shfl_xor(sk, 1, 64);
            sq += __shfl_xor(sq, 2, 64); sk += __shfl_xor(sk, 2, 64);
            sq += __shfl_xor(sq, 4, 64); sk += __shfl_xor(sk, 4, 64);
            sq += __shfl_xor(sq, 8, 64); sk += __shfl_xor(sk, 8, 64);
            qs[i] = 1.f / fmaxf(sqrtf(sq), 1e-12f);
            ks[i] = 1.f / fmaxf(sqrtf(sk), 1e-12f);
        }
        {   // V round -> gf partials
            const short8 bV0 = *(const short8*)(wsF2 + 4 * 512 + lane * 8);
            const short8 bV1 = *(const short8*)(wsF2 + 5 * 512 + lane * 8);
            f32x4 aV0={0,0,0,0}, aV1={0,0,0,0};
            aV0 = __builtin_amdgcn_mfma_f32_16x16x32_bf16(av, bV0, aV0, 0, 0, 0);
            aV1 = __builtin_amdgcn_mfma_f32_16x16x32_bf16(av, bV1, aV1, 0, 0, 0);
            float p0 = 0.f, p1 = 0.f;
            #pragma unroll
            for (int i = 0; i < 4; ++i) {
                p0 += (aK0[i] * ks[i]) * aV0[i];
                p1 += (aK1[i] * ks[i]) * aV1[i];
            }
            p0 += __shfl_xor(p0, 16, 64); p1 += __shfl_xor(p1, 16, 64);
            p0 += __shfl_xor(p0, 32, 64); p1 += __shfl_xor(p1, 32, 64);
            if (lane < 16) {
                gfp[ct * 32 + lane]      = p0;
                gfp[ct * 32 + 16 + lane] = p1;
            }
        }
        {   // G round -> qg
            const short8 bG0 = *(const short8*)(wsF2 + 6 * 512 + lane * 8);
            const short8 bG1 = *(const short8*)(wsF2 + 7 * 512 + lane * 8);
            f32x4 aG0={0,0,0,0}, aG1={0,0,0,0};
            aG0 = __builtin_amdgcn_mfma_f32_16x16x32_bf16(av, bG0, aG0, 0, 0, 0);
            aG1 = __builtin_amdgcn_mfma_f32_16x16x32_bf16(av, bG1, aG1, 0, 0, 0);
            const float bgv0 = bg[col0], bgv1 = bg[col1];
            #pragma unroll
            for (int i = 0; i < 4; ++i) {
                const int c = ct * 16 + (lane >> 4) * 4 + i;
                const float g0 = 1.f / (1.f + __expf(-(aG0[i] + bgv0)));
                const float g1 = 1.f / (1.f + __expf(-(aG1[i] + bgv1)));
                qg[c * 32 + col0] = f2bf(aQ0[i] * qs[i] * g0);
                qg[c * 32 + col1] = f2bf(aQ1[i] * qs[i] * g1);
            }
        }
    } else if (t >= 256 && t < 384) {
        const int d0 = (t - 256) * 2;
        float s1a = 0.f, s2a = 0.f, s1b = 0.f, s2b = 0.f;
        #pragma unroll 8
        for (int c = 0; c < CC; ++c) {
            const ushort2 u = *(const ushort2*)&hbf[hswz(c, d0)];
            const float va = b2f(u.x), vb = b2f(u.y);
            s1a += va; s2a += va * va;
            s1b += vb; s2b += vb * vb;
        }
        cv_s[d0]     = (s2a - s1a * s1a * (1.f / 64.f)) * (1.f / 63.f);
        cv_s[d0 + 1] = (s2b - s1b * s1b * (1.f / 64.f)) * (1.f / 63.f);
    }
    __syncthreads();

    // ---- P2: [t<256] Abuf = qg*gf -> lowbuf   [t512-575] hid = gelu(cv@W1+b1) full-dot ----
    if (t < 256) {
        const int r = t & 31, cb = t >> 5;
        const float gf = gfp[r] + gfp[32 + r] + gfp[64 + r] + gfp[96 + r];
        #pragma unroll
        for (int k = 0; k < 8; ++k) {
            const int c = cb * 8 + k;
            lowbuf[nswz(c, r)] = f2bf(b2f((unsigned short)qg[c * 32 + r]) * gf);
        }
    } else if (t >= 512 && t < 576) {
        const int j = t - 512;
        const float* w1row = wsW1T + j * 256;
        float s = b1[j];
        #pragma unroll 8
        for (int ii = 0; ii < 64; ++ii) {
            const float4 wv  = *(const float4*)(w1row + ii * 4);
            const float4 cvv = *(const float4*)&cv_s[ii * 4];
            s += cvv.x * wv.x + cvv.y * wv.y + cvv.z * wv.z + cvv.w * wv.w;
        }
        hid_s[j] = 0.5f * s * (1.f + erff(s * 0.70710678118654752f));
    }
    __syncthreads();

    // ---- P3: [w0-7] S8 MFMA x8 -> regs (B-frags L2-direct)   [t512-767] gate full-dot ----
    f32x4 s8acc[8];
    if (w < 8) {
        const int ct = w & 3, dg = w >> 2;
        const int arow = ct * 16 + (lane & 15);
        const int kofs = (lane >> 4) * 8;
        const short8 a = *(const short8*)&lowbuf[nswz(arow, kofs)];
        #pragma unroll
        for (int j = 0; j < 8; ++j) {
            const int dt = dg * 8 + j;
            const short8 bf = *(const short8*)(wsF3 + dt * 512 + lane * 8);
            f32x4 z = {0.f, 0.f, 0.f, 0.f};
            s8acc[j] = __builtin_amdgcn_mfma_f32_16x16x32_bf16(a, bf, z, 0, 0, 0);
        }
    } else if (t >= 512 && t < 768) {
        const int d = t - 512;
        const float* w2row = wsW2T + d * 64;
        float s = b2[d];
        #pragma unroll
        for (int ii = 0; ii < 16; ++ii) {
            const float4 wv = *(const float4*)(w2row + ii * 4);
            const float4 hv = *(const float4*)&hid_s[ii * 4];
            s += hv.x * wv.x + hv.y * wv.y + hv.z * wv.z + hv.w * wv.w;
        }
        gate_s[d] = 1.f / (1.f + __expf(-s));
    }
    __syncthreads();

    // ---- P4: fused residual store: out = x_bf16 + gate*(acc+bu) ----
    if (w < 8) {
        const int ct = w & 3, dg = w >> 2;
        #pragma unroll
        for (int j = 0; j < 8; ++j) {
            const int col = (dg * 8 + j) * 16 + (lane & 15);
            const float gt  = gate_s[col];
            const float buv = bu[col];
            #pragma unroll
            for (int i = 0; i < 4; ++i) {
                const int c = ct * 16 + (lane >> 4) * 4 + i;
                const float xv = b2f((unsigned short)hbf[hswz(c, col)]);
                out[rowbase + (size_t)c * (PB * DD) + col] = xv + gt * (s8acc[j][i] + buv);
            }
        }
    }
}

extern "C" void kernel_launch(void* const* d_in, const int* in_sizes, int n_in,
                              void* d_out, int out_size, void* d_ws, size_t ws_size,
                              hipStream_t stream) {
    (void)in_sizes; (void)n_in; (void)out_size; (void)ws_size;
    const float* x    = (const float*)d_in[0];
    const float* ln_g = (const float*)d_in[1];
    const float* ln_b = (const float*)d_in[2];
    const float* Wd   = (const float*)d_in[3];
    const float* bd   = (const float*)d_in[4];
    const float* Wq   = (const float*)d_in[5];
    const float* Wk   = (const float*)d_in[6];
    const float* Wv   = (const float*)d_in[7];
    const float* Wg   = (const float*)d_in[8];
    const float* bg   = (const float*)d_in[9];
    const float* Wu   = (const float*)d_in[10];
    const float* bu   = (const float*)d_in[11];
    const float* W1   = (const float*)d_in[12];
    const float* b1   = (const float*)d_in[13];
    const float* W2   = (const float*)d_in[14];
    const float* b2   = (const float*)d_in[15];
    float* out = (float*)d_out;

    short* wsWd  = (short*)d_ws;                   // 8192 shorts @ 0
    short* wsF2  = wsWd + 8192;                    // 4096 shorts @ 16384B
    short* wsF3  = wsF2 + 4096;                    // 8192 shorts @ 24576B
    float* wsLN  = (float*)(wsWd + 20480);         // 64 floats   @ 40960B
    float* wsW1T = wsLN + 64;                      // 16384 f     @ 41216B
    float* wsW2T = wsW1T + 16384;                  // 16384 f     @ 106752B

    prep_kernel<<<dim3(1), dim3(1024), 0, stream>>>(
        ln_g, ln_b, Wd, bd, Wq, Wk, Wv, Wg, Wu, W1, W2,
        wsWd, wsF2, wsF3, wsLN, wsW1T, wsW2T);
    hydra_kernel<<<dim3(32 * PB), dim3(NT), 0, stream>>>(
        x, wsWd, wsF2, wsF3, wsLN, wsW1T, wsW2T, bg, bu, b1, b2, out);
}

// Round 14
// 159.597 us; speedup vs baseline: 1.0787x; 1.0787x over previous
//
#include <hip/hip_runtime.h>
#include <hip/hip_bf16.h>

#define DD 256
#define RR 32
#define CC 64
#define PB 96
#define NT 1024

typedef __attribute__((ext_vector_type(8))) short short8;
typedef __attribute__((ext_vector_type(4))) float f32x4;

__device__ __forceinline__ short f2bf(float f) {
    return __builtin_bit_cast(short, __float2bfloat16(f));
}
__device__ __forceinline__ float b2f(unsigned short s) {
    union { unsigned u; float f; } v; v.u = ((unsigned)s) << 16;
    return v.f;
}

// [64][256] bf16: 8-elem-block XOR swizzle by (row&7)
__device__ __forceinline__ int hswz(int c, int d) {
    return c * 256 + (d ^ ((c & 7) << 3));
}
// [*][32] bf16: 8-elem-block XOR swizzle by ((row>>1)&3)
__device__ __forceinline__ int nswz(int r, int k) {
    return r * 32 + (k ^ (((r >> 1) & 3) << 3));
}

// ============ prep kernel: gWd^T swizzled + Wqkvg^T swizzled + Wu B-frags + fp32 transposes ============
__global__ __launch_bounds__(1024, 1)
void prep_kernel(const float* __restrict__ ln_g, const float* __restrict__ ln_b,
                 const float* __restrict__ Wd, const float* __restrict__ bd,
                 const float* __restrict__ Wq, const float* __restrict__ Wk,
                 const float* __restrict__ Wv, const float* __restrict__ Wg,
                 const float* __restrict__ Wu,
                 const float* __restrict__ W1, const float* __restrict__ W2,
                 short* __restrict__ wsWd, short* __restrict__ wsQKVG,
                 short* __restrict__ wsF3, float* __restrict__ wsLN,
                 float* __restrict__ wsW1T, float* __restrict__ wsW2T)
{
    __shared__ float redp[2048];
    const int t = threadIdx.x;
    {   // gWd^T swizzled image + ln-fold partials
        const int r = t >> 5, dblk = t & 31;
        short8 vv;
        float sa = 0.f, sb = 0.f;
        #pragma unroll
        for (int j = 0; j < 8; ++j) {
            const int d = dblk * 8 + j;
            const float wd = Wd[d * RR + r];
            const float g  = ln_g[d];
            vv[j] = f2bf(g * wd);
            sa += g * wd;
            sb += ln_b[d] * wd;
        }
        *(short8*)&wsWd[r * 256 + ((dblk ^ (r & 7)) << 3)] = vv;
        redp[r * 32 + dblk]        = sa;
        redp[1024 + r * 32 + dblk] = sb;
    }
    if (t < 512) {  // Wqkvg^T swizzled images (LDS-staged path)
        const int m = t >> 7, rr2 = (t >> 2) & 31, kg = t & 3;
        const float* Wm = (m == 0) ? Wq : (m == 1) ? Wk : (m == 2) ? Wv : Wg;
        short8 vv;
        #pragma unroll
        for (int j = 0; j < 8; ++j)
            vv[j] = f2bf(Wm[(kg * 8 + j) * RR + rr2]);
        *(short8*)&wsQKVG[m * 1024 + rr2 * 32 + ((kg ^ ((rr2 >> 1) & 3)) << 3)] = vv;
    }
    {   // wsF3: Wu B-frags (L2-direct path), f = dt: lane l, j -> Wu[(l>>4)*8+j][f*16+(l&15)]
        const int f = t >> 6, l = t & 63;
        const int d = f * 16 + (l & 15);
        short8 v;
        #pragma unroll
        for (int j = 0; j < 8; ++j) {
            const int r = (l >> 4) * 8 + j;
            v[j] = f2bf(Wu[r * DD + d]);
        }
        *(short8*)&wsF3[f * 512 + l * 8] = v;
    }
    #pragma unroll
    for (int rep = 0; rep < 16; ++rep) {   // W1T[j][d] (64x256 fp32)
        const int id = rep * 1024 + t;
        const int j = id >> 8, d = id & 255;
        wsW1T[j * 256 + d] = W1[d * 64 + j];
    }
    #pragma unroll
    for (int rep = 0; rep < 16; ++rep) {   // W2T[d][j] (256x64 fp32)
        const int id = rep * 1024 + t;
        const int d = id >> 6, j = id & 63;
        wsW2T[d * 64 + j] = W2[j * 256 + d];
    }
    __syncthreads();
    if (t < 32) {
        float s = 0.f;
        #pragma unroll
        for (int g = 0; g < 32; ++g) s += redp[t * 32 + g];
        wsLN[t] = s;                       // ln_a
    } else if (t < 64) {
        const int r = t - 32;
        float s = 0.f;
        #pragma unroll
        for (int g = 0; g < 32; ++g) s += redp[1024 + r * 32 + g];
        wsLN[t] = s + bd[r];               // ln_bv
    }
}

// ================= main kernel: 5 barriers, all phases 16-wave-wide =================
__global__ __launch_bounds__(NT, 8)
void hydra_kernel(const float* __restrict__ x,
                  const short* __restrict__ wsWd, const short* __restrict__ wsQKVG,
                  const short* __restrict__ wsF3, const float* __restrict__ wsLN,
                  const float* __restrict__ wsW1T, const float* __restrict__ wsW2T,
                  const float* __restrict__ bg,
                  const float* __restrict__ bu,
                  const float* __restrict__ b1, const float* __restrict__ b2,
                  float* __restrict__ out)
{
    __shared__ short hbf[CC * DD];      // 32 KB h tile bf16 swizzled (residual source, live to end)
    __shared__ short wreg[RR * DD];     // 16 KB: gWd^T (P0-P1) -> qkvg (P2-P3)
    __shared__ short qg[CC * RR];       // 4 KB  Q_n*G bf16 [c][r]
    __shared__ short lowbuf[CC * RR];   // 4 KB  hlow -> Abuf (swizzled nswz)
    __shared__ float redB[2048];        // 8 KB  chanvar partials
    __shared__ float redC[1024];        // 4 KB  LN partials (P0->P1): [c][8] float2
    __shared__ float gfp[128];          // 512B  gf partials [4][32]
    __shared__ float mu_s[CC], rstd_s[CC];
    __shared__ float cv_s[DD], gate_s[DD];
    __shared__ float hid_s[64];
    __shared__ float ln_a[RR], ln_bv[RR];

    const int t    = threadIdx.x;
    const int lane = t & 63;
    const int w    = t >> 6;
    const int bp   = blockIdx.x;
    const int b    = bp / PB;
    const int p    = bp - b * PB;
    const size_t rowbase = (size_t)(b * CC) * PB * DD + (size_t)p * DD;

    // ---- P0: load x -> hbf bf16 swizzled; LN partials (3-stage); copy gWd^T + ln vectors ----
    #pragma unroll
    for (int i = 0; i < 4; ++i) {
        const int c = w * 4 + i;
        const float4 v = *(const float4*)(x + rowbase + (size_t)c * (PB * DD) + 4 * lane);
        float s1 = v.x + v.y + v.z + v.w;
        float s2 = v.x * v.x + v.y * v.y + v.z * v.z + v.w * v.w;
        s1 += __shfl_xor(s1, 1, 64); s2 += __shfl_xor(s2, 1, 64);
        s1 += __shfl_xor(s1, 2, 64); s2 += __shfl_xor(s2, 2, 64);
        s1 += __shfl_xor(s1, 4, 64); s2 += __shfl_xor(s2, 4, 64);
        if ((lane & 7) == 0)
            *(float2*)&redC[(c * 8 + (lane >> 3)) * 2] = make_float2(s1, s2);
        ushort4 pk;
        pk.x = (unsigned short)f2bf(v.x); pk.y = (unsigned short)f2bf(v.y);
        pk.z = (unsigned short)f2bf(v.z); pk.w = (unsigned short)f2bf(v.w);
        *(ushort4*)&hbf[hswz(c, 4 * lane)] = pk;
    }
    *(short8*)&wreg[t * 8] = *(const short8*)&wsWd[t * 8];
    if (t < 32)              ln_a[t]       = wsLN[t];
    else if (t < 64)         ln_bv[t - 32] = wsLN[t];
    __syncthreads();

    // ---- P1: [w0-7] S3 MFMA (h @ gWd)   [w8-15] chan_var partials + LN finalize ----
    f32x4 s3acc = {0.f, 0.f, 0.f, 0.f};
    if (w < 8) {
        const int ct = w >> 1, rt = w & 1;
        const int arow = ct * 16 + (lane & 15);
        const int brow = rt * 16 + (lane & 15);
        const int ksub = lane >> 4;
        #pragma unroll
        for (int step = 0; step < 8; ++step) {
            const short8 a  = *(const short8*)&hbf[hswz(arow, step * 32 + ksub * 8)];
            const short8 bf = *(const short8*)&wreg[hswz(brow, step * 32 + ksub * 8)];
            s3acc = __builtin_amdgcn_mfma_f32_16x16x32_bf16(a, bf, s3acc, 0, 0, 0);
        }
    } else {
        const int idx = t - 512;                 // 0..511
        const int dp  = idx & 127;
        const int rg  = idx >> 7;
        const int d0  = dp * 2;
        float s1a = 0.f, s1b = 0.f, s2a = 0.f, s2b = 0.f;
        #pragma unroll
        for (int i = 0; i < 16; ++i) {
            const int c = rg * 16 + i;
            const ushort2 u = *(const ushort2*)&hbf[hswz(c, d0)];
            const float va = b2f(u.x), vb = b2f(u.y);
            s1a += va; s2a += va * va;
            s1b += vb; s2b += vb * vb;
        }
        *(float2*)&redB[rg * 256 + d0]        = make_float2(s1a, s1b);
        *(float2*)&redB[1024 + rg * 256 + d0] = make_float2(s2a, s2b);
        if (idx < 64) {                          // LN finalize for row c=idx
            const int c = idx;
            float s1 = 0.f, s2 = 0.f;
            #pragma unroll
            for (int g = 0; g < 8; ++g) {
                const float2 pr = *(const float2*)&redC[(c * 8 + g) * 2];
                s1 += pr.x; s2 += pr.y;
            }
            const float mu = s1 * (1.f / 256.f);
            mu_s[c]   = mu;
            rstd_s[c] = rsqrtf(s2 * (1.f / 256.f) - mu * mu + 1e-5f);
        }
    }
    __syncthreads();

    // ---- P2: [w0-7] S3 epilogue -> lowbuf   [w8-15] copy qkvg ; cv finalize (t<256) ----
    if (w < 8) {
        const int ct = w >> 1, rt = w & 1;
        const int col = rt * 16 + (lane & 15);
        const float la = ln_a[col], lb = ln_bv[col];
        #pragma unroll
        for (int i = 0; i < 4; ++i) {
            const int c = ct * 16 + (lane >> 4) * 4 + i;
            const float rs = rstd_s[c];
            const float hl = rs * s3acc[i] - rs * mu_s[c] * la + lb;
            lowbuf[nswz(c, col)] = f2bf(hl);
        }
    } else {
        const int idx = t - 512;
        *(short8*)&wreg[idx * 8] = *(const short8*)&wsQKVG[idx * 8];
    }
    if (t < 256) {
        const float S1 = redB[t] + redB[256 + t] + redB[512 + t] + redB[768 + t];
        const float S2 = redB[1024 + t] + redB[1280 + t] + redB[1536 + t] + redB[1792 + t];
        cv_s[t] = (S2 - S1 * S1 * (1.f / 64.f)) * (1.f / 63.f);
    }
    __syncthreads();

    // ---- P3: [w0-7] S5 MFMA (QG / KV) -> qg + in-wave gf   [w8-15] W1 full-dot -> hid (wave-local) ----
    if (w < 8) {
        const int ct = w >> 1, pair = w & 1;
        const int mA = pair ? 1 : 0;   // K or Q (l2-normalized)
        const int mB = pair ? 2 : 3;   // V or G
        const int arow = ct * 16 + (lane & 15);
        const int ksub = lane >> 4;
        const short8 a = *(const short8*)&lowbuf[nswz(arow, ksub * 8)];
        f32x4 aA0 = {0,0,0,0}, aA1 = {0,0,0,0}, aB0 = {0,0,0,0}, aB1 = {0,0,0,0};
        {
            const int br0 = (lane & 15), br1 = 16 + (lane & 15);
            const short8 bA0 = *(const short8*)&wreg[mA * 1024 + nswz(br0, ksub * 8)];
            const short8 bA1 = *(const short8*)&wreg[mA * 1024 + nswz(br1, ksub * 8)];
            const short8 bB0 = *(const short8*)&wreg[mB * 1024 + nswz(br0, ksub * 8)];
            const short8 bB1 = *(const short8*)&wreg[mB * 1024 + nswz(br1, ksub * 8)];
            aA0 = __builtin_amdgcn_mfma_f32_16x16x32_bf16(a, bA0, aA0, 0, 0, 0);
            aA1 = __builtin_amdgcn_mfma_f32_16x16x32_bf16(a, bA1, aA1, 0, 0, 0);
            aB0 = __builtin_amdgcn_mfma_f32_16x16x32_bf16(a, bB0, aB0, 0, 0, 0);
            aB1 = __builtin_amdgcn_mfma_f32_16x16x32_bf16(a, bB1, aB1, 0, 0, 0);
        }
        float qs[4];
        #pragma unroll
        for (int i = 0; i < 4; ++i) {
            float ss = aA0[i] * aA0[i] + aA1[i] * aA1[i];
            ss += __shfl_xor(ss, 1, 64);
            ss += __shfl_xor(ss, 2, 64);
            ss += __shfl_xor(ss, 4, 64);
            ss += __shfl_xor(ss, 8, 64);
            qs[i] = 1.f / fmaxf(sqrtf(ss), 1e-12f);
        }
        const int col0 = (lane & 15), col1 = 16 + (lane & 15);
        if (pair == 0) {
            const float bgv0 = bg[col0], bgv1 = bg[col1];
            #pragma unroll
            for (int i = 0; i < 4; ++i) {
                const int c = ct * 16 + (lane >> 4) * 4 + i;
                const float g0 = 1.f / (1.f + __expf(-(aB0[i] + bgv0)));
                const float g1 = 1.f / (1.f + __expf(-(aB1[i] + bgv1)));
                qg[c * 32 + col0] = f2bf(aA0[i] * qs[i] * g0);
                qg[c * 32 + col1] = f2bf(aA1[i] * qs[i] * g1);
            }
        } else {
            // K_n * V, summed over this wave's 16 rows in-register
            float p0 = 0.f, p1 = 0.f;
            #pragma unroll
            for (int i = 0; i < 4; ++i) {
                p0 += (aA0[i] * qs[i]) * aB0[i];
                p1 += (aA1[i] * qs[i]) * aB1[i];
            }
            p0 += __shfl_xor(p0, 16, 64); p1 += __shfl_xor(p1, 16, 64);
            p0 += __shfl_xor(p0, 32, 64); p1 += __shfl_xor(p1, 32, 64);
            if (lane < 16) {
                gfp[ct * 32 + lane]      = p0;
                gfp[ct * 32 + 16 + lane] = p1;
            }
        }
    } else {
        // W1 full-dot, wave-local: j = (w-8)*8 + (lane>>3), chunk q = lane&7 over 32 d's
        const int j = (w - 8) * 8 + (lane >> 3);
        const int q = lane & 7;
        const float* w1row = wsW1T + j * 256 + q * 32;
        float s = 0.f;
        #pragma unroll
        for (int ii = 0; ii < 8; ++ii) {
            const float4 wv  = *(const float4*)(w1row + ii * 4);
            const float4 cvv = *(const float4*)&cv_s[q * 32 + ii * 4];
            s += cvv.x * wv.x + cvv.y * wv.y + cvv.z * wv.z + cvv.w * wv.w;
        }
        s += __shfl_xor(s, 1, 64);
        s += __shfl_xor(s, 2, 64);
        s += __shfl_xor(s, 4, 64);
        if (q == 0) {
            const float z = s + b1[j];
            hid_s[j] = 0.5f * z * (1.f + erff(z * 0.70710678118654752f));
        }
    }
    __syncthreads();

    // ---- P4: [t<256] Abuf = qg*gf -> lowbuf   [256<=t<512] gate full-dot ----
    if (t < 256) {
        const int r = t & 31, c0 = t >> 5, c1 = (t >> 5) + 32;
        const float gf = gfp[r] + gfp[32 + r] + gfp[64 + r] + gfp[96 + r];
        lowbuf[nswz(c0, r)] = f2bf(b2f((unsigned short)qg[c0 * 32 + r]) * gf);
        lowbuf[nswz(c1, r)] = f2bf(b2f((unsigned short)qg[c1 * 32 + r]) * gf);
    } else if (t < 512) {
        const int d = t - 256;
        const float* w2row = wsW2T + d * 64;
        float s = b2[d];
        #pragma unroll
        for (int ii = 0; ii < 16; ++ii) {
            const float4 wv = *(const float4*)(w2row + ii * 4);
            const float4 hv = *(const float4*)&hid_s[ii * 4];
            s += hv.x * wv.x + hv.y * wv.y + hv.z * wv.z + hv.w * wv.w;
        }
        gate_s[d] = 1.f / (1.f + __expf(-s));
    }
    __syncthreads();

    // ---- P5: S8 MFMA (Abuf @ Wu frags L2-direct) + fused residual store ----
    {
        const int ct = w & 3, dg = w >> 2;
        const int arow = ct * 16 + (lane & 15);
        const int ksub = lane >> 4;
        const short8 a = *(const short8*)&lowbuf[nswz(arow, ksub * 8)];
        #pragma unroll
        for (int j = 0; j < 4; ++j) {
            const int dt = dg * 4 + j;
            const int col = dt * 16 + (lane & 15);
            const short8 bf = *(const short8*)(wsF3 + dt * 512 + lane * 8);
            f32x4 acc = {0.f, 0.f, 0.f, 0.f};
            acc = __builtin_amdgcn_mfma_f32_16x16x32_bf16(a, bf, acc, 0, 0, 0);
            const float gt  = gate_s[col];
            const float buv = bu[col];
            #pragma unroll
            for (int i = 0; i < 4; ++i) {
                const int c = ct * 16 + (lane >> 4) * 4 + i;
                const float xv = b2f((unsigned short)hbf[hswz(c, col)]);
                out[rowbase + (size_t)c * (PB * DD) + col] = xv + gt * (acc[i] + buv);
            }
        }
    }
}

extern "C" void kernel_launch(void* const* d_in, const int* in_sizes, int n_in,
                              void* d_out, int out_size, void* d_ws, size_t ws_size,
                              hipStream_t stream) {
    (void)in_sizes; (void)n_in; (void)out_size; (void)ws_size;
    const float* x    = (const float*)d_in[0];
    const float* ln_g = (const float*)d_in[1];
    const float* ln_b = (const float*)d_in[2];
    const float* Wd   = (const float*)d_in[3];
    const float* bd   = (const float*)d_in[4];
    const float* Wq   = (const float*)d_in[5];
    const float* Wk   = (const float*)d_in[6];
    const float* Wv   = (const float*)d_in[7];
    const float* Wg   = (const float*)d_in[8];
    const float* bg   = (const float*)d_in[9];
    const float* Wu   = (const float*)d_in[10];
    const float* bu   = (const float*)d_in[11];
    const float* W1   = (const float*)d_in[12];
    const float* b1   = (const float*)d_in[13];
    const float* W2   = (const float*)d_in[14];
    const float* b2   = (const float*)d_in[15];
    float* out = (float*)d_out;

    short* wsWd   = (short*)d_ws;                  // 8192 shorts @ 0
    short* wsQKVG = wsWd + 8192;                   // 4096 shorts @ 16384B
    short* wsF3   = wsQKVG + 4096;                 // 8192 shorts @ 24576B
    float* wsLN   = (float*)(wsWd + 20480);        // 64 floats   @ 40960B
    float* wsW1T  = wsLN + 64;                     // 16384 f     @ 41216B
    float* wsW2T  = wsW1T + 16384;                 // 16384 f     @ 106752B

    prep_kernel<<<dim3(1), dim3(1024), 0, stream>>>(
        ln_g, ln_b, Wd, bd, Wq, Wk, Wv, Wg, Wu, W1, W2,
        wsWd, wsQKVG, wsF3, wsLN, wsW1T, wsW2T);
    hydra_kernel<<<dim3(32 * PB), dim3(NT), 0, stream>>>(
        x, wsWd, wsQKVG, wsF3, wsLN, wsW1T, wsW2T, bg, bu, b1, b2, out);
}

// Round 15
// 159.165 us; speedup vs baseline: 1.0817x; 1.0027x over previous
//
#include <hip/hip_runtime.h>
#include <hip/hip_bf16.h>

#define DD 256
#define RR 32
#define CC 64
#define PB 96
#define NT 1024

typedef __attribute__((ext_vector_type(8))) short short8;
typedef __attribute__((ext_vector_type(4))) float f32x4;

__device__ __forceinline__ short f2bf(float f) {
    return __builtin_bit_cast(short, __float2bfloat16(f));
}
__device__ __forceinline__ float b2f(unsigned short s) {
    union { unsigned u; float f; } v; v.u = ((unsigned)s) << 16;
    return v.f;
}

// [64][256] bf16: 8-elem-block XOR swizzle by (row&7)
__device__ __forceinline__ int hswz(int c, int d) {
    return c * 256 + (d ^ ((c & 7) << 3));
}
// [*][32] bf16: 8-elem-block XOR swizzle by ((row>>1)&3)
__device__ __forceinline__ int nswz(int r, int k) {
    return r * 32 + (k ^ (((r >> 1) & 3) << 3));
}

// ============ prep kernel: gWd^T swizzled + Wqkvg^T swizzled + Wu B-frags + fp32 transposes ============
__global__ __launch_bounds__(1024, 1)
void prep_kernel(const float* __restrict__ ln_g, const float* __restrict__ ln_b,
                 const float* __restrict__ Wd, const float* __restrict__ bd,
                 const float* __restrict__ Wq, const float* __restrict__ Wk,
                 const float* __restrict__ Wv, const float* __restrict__ Wg,
                 const float* __restrict__ Wu,
                 const float* __restrict__ W1, const float* __restrict__ W2,
                 short* __restrict__ wsWd, short* __restrict__ wsQKVG,
                 short* __restrict__ wsF3, float* __restrict__ wsLN,
                 float* __restrict__ wsW1T, float* __restrict__ wsW2T)
{
    __shared__ float redp[2048];
    const int t = threadIdx.x;
    {   // gWd^T swizzled image + ln-fold partials
        const int r = t >> 5, dblk = t & 31;
        short8 vv;
        float sa = 0.f, sb = 0.f;
        #pragma unroll
        for (int j = 0; j < 8; ++j) {
            const int d = dblk * 8 + j;
            const float wd = Wd[d * RR + r];
            const float g  = ln_g[d];
            vv[j] = f2bf(g * wd);
            sa += g * wd;
            sb += ln_b[d] * wd;
        }
        *(short8*)&wsWd[r * 256 + ((dblk ^ (r & 7)) << 3)] = vv;
        redp[r * 32 + dblk]        = sa;
        redp[1024 + r * 32 + dblk] = sb;
    }
    if (t < 512) {  // Wqkvg^T swizzled images (LDS-staged path)
        const int m = t >> 7, rr2 = (t >> 2) & 31, kg = t & 3;
        const float* Wm = (m == 0) ? Wq : (m == 1) ? Wk : (m == 2) ? Wv : Wg;
        short8 vv;
        #pragma unroll
        for (int j = 0; j < 8; ++j)
            vv[j] = f2bf(Wm[(kg * 8 + j) * RR + rr2]);
        *(short8*)&wsQKVG[m * 1024 + rr2 * 32 + ((kg ^ ((rr2 >> 1) & 3)) << 3)] = vv;
    }
    {   // wsF3: Wu B-frags (L2-direct path), f = dt: lane l, j -> Wu[(l>>4)*8+j][f*16+(l&15)]
        const int f = t >> 6, l = t & 63;
        const int d = f * 16 + (l & 15);
        short8 v;
        #pragma unroll
        for (int j = 0; j < 8; ++j) {
            const int r = (l >> 4) * 8 + j;
            v[j] = f2bf(Wu[r * DD + d]);
        }
        *(short8*)&wsF3[f * 512 + l * 8] = v;
    }
    #pragma unroll
    for (int rep = 0; rep < 16; ++rep) {   // W1T[j][d] (64x256 fp32)
        const int id = rep * 1024 + t;
        const int j = id >> 8, d = id & 255;
        wsW1T[j * 256 + d] = W1[d * 64 + j];
    }
    #pragma unroll
    for (int rep = 0; rep < 16; ++rep) {   // W2T[d][j] (256x64 fp32)
        const int id = rep * 1024 + t;
        const int d = id >> 6, j = id & 63;
        wsW2T[d * 64 + j] = W2[j * 256 + d];
    }
    __syncthreads();
    if (t < 32) {
        float s = 0.f;
        #pragma unroll
        for (int g = 0; g < 32; ++g) s += redp[t * 32 + g];
        wsLN[t] = s;                       // ln_a
    } else if (t < 64) {
        const int r = t - 32;
        float s = 0.f;
        #pragma unroll
        for (int g = 0; g < 32; ++g) s += redp[1024 + r * 32 + g];
        wsLN[t] = s + bd[r];               // ln_bv
    }
}

// ================= main kernel: 4 barriers, 5 width-balanced phases =================
__global__ __launch_bounds__(NT, 8)
void hydra_kernel(const float* __restrict__ x,
                  const short* __restrict__ wsWd, const short* __restrict__ wsQKVG,
                  const short* __restrict__ wsF3, const float* __restrict__ wsLN,
                  const float* __restrict__ wsW1T, const float* __restrict__ wsW2T,
                  const float* __restrict__ bg,
                  const float* __restrict__ bu,
                  const float* __restrict__ b1, const float* __restrict__ b2,
                  float* __restrict__ out)
{
    __shared__ short hbf[CC * DD];      // 32 KB h tile bf16 swizzled (residual source, live to end)
    __shared__ short wreg[RR * DD];     // 16 KB: gWd^T (P0-P1) -> qkvg (P2-P3)
    __shared__ short qg[CC * RR];       // 4 KB  Q_n*G bf16, nswz-swizzled
    __shared__ short lowbuf[CC * RR];   // 4 KB  hlow (nswz)
    __shared__ float redC[1024];        // 4 KB  LN partials (P0->P1): [c][8] float2
    __shared__ float gfp[128];          // 512B  gf partials [4][32]
    __shared__ float mu_s[CC], rstd_s[CC];
    __shared__ float cv_s[DD], gate_s[DD];
    __shared__ float hid_s[64];
    __shared__ float ln_a[RR], ln_bv[RR];

    const int t    = threadIdx.x;
    const int lane = t & 63;
    const int w    = t >> 6;
    const int bp   = blockIdx.x;
    const int b    = bp / PB;
    const int p    = bp - b * PB;
    const size_t rowbase = (size_t)(b * CC) * PB * DD + (size_t)p * DD;

    // ---- P0: load x -> hbf bf16 swizzled; LN partials (3-stage); copy gWd^T + ln vectors ----
    #pragma unroll
    for (int i = 0; i < 4; ++i) {
        const int c = w * 4 + i;
        const float4 v = *(const float4*)(x + rowbase + (size_t)c * (PB * DD) + 4 * lane);
        float s1 = v.x + v.y + v.z + v.w;
        float s2 = v.x * v.x + v.y * v.y + v.z * v.z + v.w * v.w;
        s1 += __shfl_xor(s1, 1, 64); s2 += __shfl_xor(s2, 1, 64);
        s1 += __shfl_xor(s1, 2, 64); s2 += __shfl_xor(s2, 2, 64);
        s1 += __shfl_xor(s1, 4, 64); s2 += __shfl_xor(s2, 4, 64);
        if ((lane & 7) == 0)
            *(float2*)&redC[(c * 8 + (lane >> 3)) * 2] = make_float2(s1, s2);
        ushort4 pk;
        pk.x = (unsigned short)f2bf(v.x); pk.y = (unsigned short)f2bf(v.y);
        pk.z = (unsigned short)f2bf(v.z); pk.w = (unsigned short)f2bf(v.w);
        *(ushort4*)&hbf[hswz(c, 4 * lane)] = pk;
    }
    *(short8*)&wreg[t * 8] = *(const short8*)&wsWd[t * 8];
    if (t < 32)              ln_a[t]       = wsLN[t];
    else if (t < 64)         ln_bv[t - 32] = wsLN[t];
    __syncthreads();

    // ---- P1: [w0-7] S3 MFMA   [w8-11] chan_var direct (1 col/thread)   [w12-15] LN finalize ----
    f32x4 s3acc = {0.f, 0.f, 0.f, 0.f};
    if (w < 8) {
        const int ct = w >> 1, rt = w & 1;
        const int arow = ct * 16 + (lane & 15);
        const int brow = rt * 16 + (lane & 15);
        const int ksub = lane >> 4;
        #pragma unroll
        for (int step = 0; step < 8; ++step) {
            const short8 a  = *(const short8*)&hbf[hswz(arow, step * 32 + ksub * 8)];
            const short8 bf = *(const short8*)&wreg[hswz(brow, step * 32 + ksub * 8)];
            s3acc = __builtin_amdgcn_mfma_f32_16x16x32_bf16(a, bf, s3acc, 0, 0, 0);
        }
    } else if (t < 768) {
        const int d = t - 512;          // one full column per thread
        float s1 = 0.f, s2 = 0.f;
        #pragma unroll 8
        for (int c = 0; c < CC; ++c) {
            const float v = b2f((unsigned short)hbf[hswz(c, d)]);
            s1 += v; s2 += v * v;
        }
        cv_s[d] = (s2 - s1 * s1 * (1.f / 64.f)) * (1.f / 63.f);
    } else if (t < 832) {
        const int c = t - 768;          // LN finalize
        float s1 = 0.f, s2 = 0.f;
        #pragma unroll
        for (int g = 0; g < 8; ++g) {
            const float2 pr = *(const float2*)&redC[(c * 8 + g) * 2];
            s1 += pr.x; s2 += pr.y;
        }
        const float mu = s1 * (1.f / 256.f);
        mu_s[c]   = mu;
        rstd_s[c] = rsqrtf(s2 * (1.f / 256.f) - mu * mu + 1e-5f);
    }
    __syncthreads();

    // ---- P2: [w0-7] S3 epilogue -> lowbuf + copy qkvg -> wreg   [w8-15] W1 full-dot -> hid ----
    if (w < 8) {
        const int ct = w >> 1, rt = w & 1;
        const int col = rt * 16 + (lane & 15);
        const float la = ln_a[col], lb = ln_bv[col];
        #pragma unroll
        for (int i = 0; i < 4; ++i) {
            const int c = ct * 16 + (lane >> 4) * 4 + i;
            const float rs = rstd_s[c];
            const float hl = rs * s3acc[i] - rs * mu_s[c] * la + lb;
            lowbuf[nswz(c, col)] = f2bf(hl);
        }
        *(short8*)&wreg[t * 8] = *(const short8*)&wsQKVG[t * 8];   // t<512: 4096 shorts
    } else {
        // W1 full-dot, wave-local: j = (w-8)*8 + (lane>>3), chunk q = lane&7 over 32 d's
        const int j = (w - 8) * 8 + (lane >> 3);
        const int q = lane & 7;
        const float* w1row = wsW1T + j * 256 + q * 32;
        float s = 0.f;
        #pragma unroll
        for (int ii = 0; ii < 8; ++ii) {
            const float4 wv  = *(const float4*)(w1row + ii * 4);
            const float4 cvv = *(const float4*)&cv_s[q * 32 + ii * 4];
            s += cvv.x * wv.x + cvv.y * wv.y + cvv.z * wv.z + cvv.w * wv.w;
        }
        s += __shfl_xor(s, 1, 64);
        s += __shfl_xor(s, 2, 64);
        s += __shfl_xor(s, 4, 64);
        if (q == 0) {
            const float z = s + b1[j];
            hid_s[j] = 0.5f * z * (1.f + erff(z * 0.70710678118654752f));
        }
    }
    __syncthreads();

    // ---- P3: [w0-7] S5 MFMA (QG / KV) -> qg(nswz) + in-wave gf   [w8-11] gate full-dot ----
    if (w < 8) {
        const int ct = w >> 1, pair = w & 1;
        const int mA = pair ? 1 : 0;   // K or Q (l2-normalized)
        const int mB = pair ? 2 : 3;   // V or G
        const int arow = ct * 16 + (lane & 15);
        const int ksub = lane >> 4;
        const short8 a = *(const short8*)&lowbuf[nswz(arow, ksub * 8)];
        f32x4 aA0 = {0,0,0,0}, aA1 = {0,0,0,0}, aB0 = {0,0,0,0}, aB1 = {0,0,0,0};
        {
            const int br0 = (lane & 15), br1 = 16 + (lane & 15);
            const short8 bA0 = *(const short8*)&wreg[mA * 1024 + nswz(br0, ksub * 8)];
            const short8 bA1 = *(const short8*)&wreg[mA * 1024 + nswz(br1, ksub * 8)];
            const short8 bB0 = *(const short8*)&wreg[mB * 1024 + nswz(br0, ksub * 8)];
            const short8 bB1 = *(const short8*)&wreg[mB * 1024 + nswz(br1, ksub * 8)];
            aA0 = __builtin_amdgcn_mfma_f32_16x16x32_bf16(a, bA0, aA0, 0, 0, 0);
            aA1 = __builtin_amdgcn_mfma_f32_16x16x32_bf16(a, bA1, aA1, 0, 0, 0);
            aB0 = __builtin_amdgcn_mfma_f32_16x16x32_bf16(a, bB0, aB0, 0, 0, 0);
            aB1 = __builtin_amdgcn_mfma_f32_16x16x32_bf16(a, bB1, aB1, 0, 0, 0);
        }
        float qs[4];
        #pragma unroll
        for (int i = 0; i < 4; ++i) {
            float ss = aA0[i] * aA0[i] + aA1[i] * aA1[i];
            ss += __shfl_xor(ss, 1, 64);
            ss += __shfl_xor(ss, 2, 64);
            ss += __shfl_xor(ss, 4, 64);
            ss += __shfl_xor(ss, 8, 64);
            qs[i] = 1.f / fmaxf(sqrtf(ss), 1e-12f);
        }
        const int col0 = (lane & 15), col1 = 16 + (lane & 15);
        if (pair == 0) {
            const float bgv0 = bg[col0], bgv1 = bg[col1];
            #pragma unroll
            for (int i = 0; i < 4; ++i) {
                const int c = ct * 16 + (lane >> 4) * 4 + i;
                const float g0 = 1.f / (1.f + __expf(-(aB0[i] + bgv0)));
                const float g1 = 1.f / (1.f + __expf(-(aB1[i] + bgv1)));
                qg[nswz(c, col0)] = f2bf(aA0[i] * qs[i] * g0);
                qg[nswz(c, col1)] = f2bf(aA1[i] * qs[i] * g1);
            }
        } else {
            // K_n * V, summed over this wave's 16 rows in-register
            float p0 = 0.f, p1 = 0.f;
            #pragma unroll
            for (int i = 0; i < 4; ++i) {
                p0 += (aA0[i] * qs[i]) * aB0[i];
                p1 += (aA1[i] * qs[i]) * aB1[i];
            }
            p0 += __shfl_xor(p0, 16, 64); p1 += __shfl_xor(p1, 16, 64);
            p0 += __shfl_xor(p0, 32, 64); p1 += __shfl_xor(p1, 32, 64);
            if (lane < 16) {
                gfp[ct * 32 + lane]      = p0;
                gfp[ct * 32 + 16 + lane] = p1;
            }
        }
    } else if (t < 768) {
        const int d = t - 512;
        const float* w2row = wsW2T + d * 64;
        float s = b2[d];
        #pragma unroll
        for (int ii = 0; ii < 16; ++ii) {
            const float4 wv = *(const float4*)(w2row + ii * 4);
            const float4 hv = *(const float4*)&hid_s[ii * 4];
            s += hv.x * wv.x + hv.y * wv.y + hv.z * wv.z + hv.w * wv.w;
        }
        gate_s[d] = 1.f / (1.f + __expf(-s));
    }
    __syncthreads();

    // ---- P4: S8 MFMA (A-frag = qg*gf in-register; B-frags L2-direct) + fused residual store ----
    {
        const int ct = w & 3, dg = w >> 2;
        const int arow = ct * 16 + (lane & 15);
        const int kofs = (lane >> 4) * 8;
        // gf for this lane's k-octet (broadcast reads within 16-lane groups)
        float gfv[8];
        {
            const float4 a0 = *(const float4*)&gfp[0 * 32 + kofs];
            const float4 b0 = *(const float4*)&gfp[0 * 32 + kofs + 4];
            const float4 a1 = *(const float4*)&gfp[1 * 32 + kofs];
            const float4 b1v = *(const float4*)&gfp[1 * 32 + kofs + 4];
            const float4 a2 = *(const float4*)&gfp[2 * 32 + kofs];
            const float4 b2v = *(const float4*)&gfp[2 * 32 + kofs + 4];
            const float4 a3 = *(const float4*)&gfp[3 * 32 + kofs];
            const float4 b3 = *(const float4*)&gfp[3 * 32 + kofs + 4];
            gfv[0] = a0.x + a1.x + a2.x + a3.x;
            gfv[1] = a0.y + a1.y + a2.y + a3.y;
            gfv[2] = a0.z + a1.z + a2.z + a3.z;
            gfv[3] = a0.w + a1.w + a2.w + a3.w;
            gfv[4] = b0.x + b1v.x + b2v.x + b3.x;
            gfv[5] = b0.y + b1v.y + b2v.y + b3.y;
            gfv[6] = b0.z + b1v.z + b2v.z + b3.z;
            gfv[7] = b0.w + b1v.w + b2v.w + b3.w;
        }
        const short8 qv = *(const short8*)&qg[nswz(arow, kofs)];
        short8 a;
        #pragma unroll
        for (int j = 0; j < 8; ++j)
            a[j] = f2bf(b2f((unsigned short)qv[j]) * gfv[j]);
        #pragma unroll
        for (int j = 0; j < 4; ++j) {
            const int dt = dg * 4 + j;
            const int col = dt * 16 + (lane & 15);
            const short8 bf = *(const short8*)(wsF3 + dt * 512 + lane * 8);
            f32x4 acc = {0.f, 0.f, 0.f, 0.f};
            acc = __builtin_amdgcn_mfma_f32_16x16x32_bf16(a, bf, acc, 0, 0, 0);
            const float gt  = gate_s[col];
            const float buv = bu[col];
            #pragma unroll
            for (int i = 0; i < 4; ++i) {
                const int c = ct * 16 + (lane >> 4) * 4 + i;
                const float xv = b2f((unsigned short)hbf[hswz(c, col)]);
                out[rowbase + (size_t)c * (PB * DD) + col] = xv + gt * (acc[i] + buv);
            }
        }
    }
}

extern "C" void kernel_launch(void* const* d_in, const int* in_sizes, int n_in,
                              void* d_out, int out_size, void* d_ws, size_t ws_size,
                              hipStream_t stream) {
    (void)in_sizes; (void)n_in; (void)out_size; (void)ws_size;
    const float* x    = (const float*)d_in[0];
    const float* ln_g = (const float*)d_in[1];
    const float* ln_b = (const float*)d_in[2];
    const float* Wd   = (const float*)d_in[3];
    const float* bd   = (const float*)d_in[4];
    const float* Wq   = (const float*)d_in[5];
    const float* Wk   = (const float*)d_in[6];
    const float* Wv   = (const float*)d_in[7];
    const float* Wg   = (const float*)d_in[8];
    const float* bg   = (const float*)d_in[9];
    const float* Wu   = (const float*)d_in[10];
    const float* bu   = (const float*)d_in[11];
    const float* W1   = (const float*)d_in[12];
    const float* b1   = (const float*)d_in[13];
    const float* W2   = (const float*)d_in[14];
    const float* b2   = (const float*)d_in[15];
    float* out = (float*)d_out;

    short* wsWd   = (short*)d_ws;                  // 8192 shorts @ 0
    short* wsQKVG = wsWd + 8192;                   // 4096 shorts @ 16384B
    short* wsF3   = wsQKVG + 4096;                 // 8192 shorts @ 24576B
    float* wsLN   = (float*)(wsWd + 20480);        // 64 floats   @ 40960B
    float* wsW1T  = wsLN + 64;                     // 16384 f     @ 41216B
    float* wsW2T  = wsW1T + 16384;                 // 16384 f     @ 106752B

    prep_kernel<<<dim3(1), dim3(1024), 0, stream>>>(
        ln_g, ln_b, Wd, bd, Wq, Wk, Wv, Wg, Wu, W1, W2,
        wsWd, wsQKVG, wsF3, wsLN, wsW1T, wsW2T);
    hydra_kernel<<<dim3(32 * PB), dim3(NT), 0, stream>>>(
        x, wsWd, wsQKVG, wsF3, wsLN, wsW1T, wsW2T, bg, bu, b1, b2, out);
}